// Round 4
// baseline (122.772 us; speedup 1.0000x reference)
//
#include <hip/hip_runtime.h>
#include <math.h>

#define NROWS 4096
#define DIM   512
#define BM    128           // block tile (2x2 waves of 64x64)
#define NTILE (NROWS / BM)  // 32
#define NBLK  (NTILE * (NTILE + 1) / 2)  // 528 triangular blocks

typedef __attribute__((ext_vector_type(4))) float f32x4;
typedef __attribute__((ext_vector_type(8))) short bf16x8;

// ws layout (bytes):
// [0,       16384)   float mag[4096]
// [16384,   32768)   float row_neg[4096]
// [32768,   32776)   double loss
// [32776,   32780)   unsigned int pair_cnt
// [32800,   4227104) unsigned short Xb[4096*512]  (bf16 copy of X)
// [4227104, ...)     pairs: 3 ints each {i, j, float_bits(dist)}
#define XB_OFF   32800
#define PAIR_OFF 4227104

__device__ inline unsigned short f2bf(float f) {
    unsigned int u = __float_as_uint(f);
    unsigned int r = (u + 0x7fffu + ((u >> 16) & 1u)) >> 16;   // RTNE
    return (unsigned short)r;
}

// fused: bf16 convert + row sq-norms (reads X once)
__global__ void prep_kernel(const float* __restrict__ X,
                            unsigned short* __restrict__ Xb,
                            float* __restrict__ mag) {
    int row  = blockIdx.x * 4 + (threadIdx.x >> 6);
    int lane = threadIdx.x & 63;
    const float4* p = reinterpret_cast<const float4*>(X + (size_t)row * DIM);
    short4* o = reinterpret_cast<short4*>(Xb + (size_t)row * DIM);
    float s = 0.f;
#pragma unroll
    for (int q = lane; q < DIM / 4; q += 64) {
        float4 v = p[q];
        s += v.x * v.x + v.y * v.y + v.z * v.z + v.w * v.w;
        short4 b;
        b.x = (short)f2bf(v.x); b.y = (short)f2bf(v.y);
        b.z = (short)f2bf(v.z); b.w = (short)f2bf(v.w);
        o[q] = b;
    }
#pragma unroll
    for (int off = 32; off; off >>= 1) s += __shfl_down(s, off);
    if (lane == 0) mag[row] = s;
}

// Register-direct MFMA GEMM: no LDS, no barriers. Each wave = one 64x64 tile.
__global__ __launch_bounds__(256) void sim_reg(
        const unsigned short* __restrict__ Xb, const int* __restrict__ tgt,
        const float* __restrict__ mag, float* __restrict__ row_neg,
        unsigned int* __restrict__ pair_cnt, int* __restrict__ pairs,
        unsigned int cap) {
    const int tid  = threadIdx.x;
    const int lane = tid & 63;
    const int wid  = tid >> 6;        // 4 waves: 2x2 of 64x64
    const int wr   = wid >> 1, wc = wid & 1;
    const int l15  = lane & 15;
    const int lg   = lane >> 4;       // 0..3

    // triangular block mapping: t -> (bi, bj), bi <= bj (NTILE=32)
    int t = blockIdx.x;
    int bi = (int)((65.0f - sqrtf(4225.0f - 8.0f * (float)t)) * 0.5f);
    if (bi < 0) bi = 0;
    if (bi > NTILE - 1) bi = NTILE - 1;
    while ((65 * (bi + 1) - (bi + 1) * (bi + 1)) / 2 <= t) bi++;
    while ((65 * bi - bi * bi) / 2 > t) bi--;
    int bj = bi + (t - (65 * bi - bi * bi) / 2);
    const int rowBase = bi * BM;
    const int colBase = bj * BM;
    const bool offd = (bi != bj);

    f32x4 acc[4][4];
#pragma unroll
    for (int m = 0; m < 4; m++)
#pragma unroll
        for (int n = 0; n < 4; n++) acc[m][n] = (f32x4){0.f, 0.f, 0.f, 0.f};

    // per-lane fragment base pointers: A frag and B frag have the SAME pattern
    // (lane (lg,l15): 16B at X[base + l15][k0 + lg*8]); 64B-coalesced per wave.
    const unsigned short* pA = Xb + (size_t)(rowBase + wr * 64 + l15) * DIM + lg * 8;
    const unsigned short* pB = Xb + (size_t)(colBase + wc * 64 + l15) * DIM + lg * 8;

#define LOADF(da, db, kt)                                                     \
    {                                                                         \
        int ko = (kt) * 32;                                                   \
        da[0] = *reinterpret_cast<const bf16x8*>(pA + 0 * 16 * DIM + ko);     \
        da[1] = *reinterpret_cast<const bf16x8*>(pA + 1 * 16 * DIM + ko);     \
        da[2] = *reinterpret_cast<const bf16x8*>(pA + 2 * 16 * DIM + ko);     \
        da[3] = *reinterpret_cast<const bf16x8*>(pA + 3 * 16 * DIM + ko);     \
        db[0] = *reinterpret_cast<const bf16x8*>(pB + 0 * 16 * DIM + ko);     \
        db[1] = *reinterpret_cast<const bf16x8*>(pB + 1 * 16 * DIM + ko);     \
        db[2] = *reinterpret_cast<const bf16x8*>(pB + 2 * 16 * DIM + ko);     \
        db[3] = *reinterpret_cast<const bf16x8*>(pB + 3 * 16 * DIM + ko);     \
    }
#define MFMAF(a, b)                                                           \
    {                                                                         \
        _Pragma("unroll") for (int m = 0; m < 4; m++)                         \
            _Pragma("unroll") for (int n = 0; n < 4; n++)                     \
                acc[m][n] = __builtin_amdgcn_mfma_f32_16x16x32_bf16(          \
                    a[m], b[n], acc[m][n], 0, 0, 0);                          \
    }

    // 2-deep hand pipeline over 16 K-steps (named sets, rule #20)
    bf16x8 a0[4], b0[4], a1[4], b1[4];
    LOADF(a0, b0, 0)
#pragma unroll
    for (int kt = 0; kt < 16; kt += 2) {
        if (kt + 1 < 16) LOADF(a1, b1, kt + 1)
        MFMAF(a0, b0)
        if (kt + 2 < 16) LOADF(a0, b0, kt + 2)
        if (kt + 1 < 16) MFMAF(a1, b1)
    }
#undef LOADF
#undef MFMAF

    // ---- fused epilogue ----
    // C/D layout: col = lane&15, row = (lane>>4)*4 + reg
    int   gcol[4], tgj[4];
    float mj[4];
#pragma unroll
    for (int n = 0; n < 4; n++) {
        gcol[n] = colBase + wc * 64 + n * 16 + l15;
        tgj[n]  = tgt[gcol[n]];
        mj[n]   = mag[gcol[n]];
    }
    int   grow[4][4], tgi[4][4];
    float mi[4][4];
#pragma unroll
    for (int m = 0; m < 4; m++)
#pragma unroll
        for (int q = 0; q < 4; q++) {
            grow[m][q] = rowBase + wr * 64 + m * 16 + lg * 4 + q;
            tgi[m][q]  = tgt[grow[m][q]];
            mi[m][q]   = mag[grow[m][q]];
        }

    float negrow[4][4];
    float negcol[4] = {0.f, 0.f, 0.f, 0.f};
#pragma unroll
    for (int m = 0; m < 4; m++)
#pragma unroll
        for (int q = 0; q < 4; q++) negrow[m][q] = 0.f;

    int mycnt = 0;
#pragma unroll
    for (int m = 0; m < 4; m++)
#pragma unroll
        for (int n = 0; n < 4; n++)
#pragma unroll
            for (int q = 0; q < 4; q++) {
                float sim  = acc[m][n][q];
                float d2   = mi[m][q] + mj[n] - 2.f * sim;
                float dist = d2 > 0.f ? sqrtf(d2) : 0.f;
                if (tgi[m][q] != tgj[n]) {
                    if (dist != 0.f) {
                        float e = __expf(1.0f - dist);
                        negrow[m][q] += e;
                        if (offd) negcol[n] += e;
                    }
                } else if (grow[m][q] < gcol[n]) {
                    mycnt++;
                }
            }

    // row-side: reduce across the 16 lanes of each lane-group, 1 atomic/row
#pragma unroll
    for (int m = 0; m < 4; m++)
#pragma unroll
        for (int q = 0; q < 4; q++) {
            float v = negrow[m][q];
            v += __shfl_xor(v, 1); v += __shfl_xor(v, 2);
            v += __shfl_xor(v, 4); v += __shfl_xor(v, 8);
            if (l15 == 0) atomicAdd(&row_neg[grow[m][q]], v);
        }
    // col-side (off-diagonal tiles): reduce across lane-groups, 1 atomic/col
    if (offd) {
#pragma unroll
        for (int n = 0; n < 4; n++) {
            float v = negcol[n];
            v += __shfl_xor(v, 16); v += __shfl_xor(v, 32);
            if (lg == 0) atomicAdd(&row_neg[gcol[n]], v);
        }
    }

    // compact positive (i<j) pairs
    if (mycnt) {
        unsigned int base = atomicAdd(pair_cnt, (unsigned int)mycnt);
        unsigned int off = 0;
#pragma unroll
        for (int m = 0; m < 4; m++)
#pragma unroll
            for (int n = 0; n < 4; n++)
#pragma unroll
                for (int q = 0; q < 4; q++) {
                    if (tgi[m][q] == tgj[n] && grow[m][q] < gcol[n]) {
                        unsigned int idx = base + off;
                        if (idx < cap) {
                            float sim  = acc[m][n][q];
                            float d2   = mi[m][q] + mj[n] - 2.f * sim;
                            float dist = d2 > 0.f ? sqrtf(d2) : 0.f;
                            pairs[idx * 3 + 0] = grow[m][q];
                            pairs[idx * 3 + 1] = gcol[n];
                            pairs[idx * 3 + 2] = __float_as_int(dist);
                        }
                        off++;
                    }
                }
    }
}

__global__ void pair_kernel(const int* __restrict__ pairs,
                            const unsigned int* __restrict__ pair_cnt,
                            const float* __restrict__ row_neg,
                            unsigned int cap, double* __restrict__ loss) {
    __shared__ double red[256];
    unsigned int n = *pair_cnt;
    if (n > cap) n = cap;
    double local = 0.0;
    for (unsigned int p = blockIdx.x * blockDim.x + threadIdx.x; p < n;
         p += gridDim.x * blockDim.x) {
        int i = pairs[3 * p], j = pairs[3 * p + 1];
        float d = __int_as_float(pairs[3 * p + 2]);
        float J = logf(row_neg[i] + row_neg[j]) + d;
        if (J > 0.f) local += (double)J * (double)J;
    }
    red[threadIdx.x] = local;
    __syncthreads();
    for (int s = 128; s; s >>= 1) {
        if (threadIdx.x < (unsigned)s) red[threadIdx.x] += red[threadIdx.x + s];
        __syncthreads();
    }
    if (threadIdx.x == 0) atomicAdd(loss, red[0]);
}

__global__ void fin_kernel(const double* __restrict__ loss,
                           const unsigned int* __restrict__ pair_cnt,
                           float* __restrict__ out) {
    out[0] = (float)(*loss / (2.0 * (double)(*pair_cnt)));
}

extern "C" void kernel_launch(void* const* d_in, const int* in_sizes, int n_in,
                              void* d_out, int out_size, void* d_ws, size_t ws_size,
                              hipStream_t stream) {
    const float* X = (const float*)d_in[0];
    const int* tgt = (const int*)d_in[1];
    float* out = (float*)d_out;

    char* ws = (char*)d_ws;
    float* mag             = (float*)(ws + 0);
    float* row_neg         = (float*)(ws + 16384);
    double* loss           = (double*)(ws + 32768);
    unsigned int* pair_cnt = (unsigned int*)(ws + 32776);
    unsigned short* Xb     = (unsigned short*)(ws + XB_OFF);
    int* pairs             = (int*)(ws + PAIR_OFF);
    unsigned int cap = 0;
    if (ws_size > PAIR_OFF + 12) cap = (unsigned int)((ws_size - PAIR_OFF) / 12);

    hipMemsetAsync(ws + 16384, 0, 16400, stream);  // row_neg, loss, pair_cnt

    prep_kernel<<<NROWS / 4, 256, 0, stream>>>(X, Xb, mag);

    sim_reg<<<NBLK, 256, 0, stream>>>(Xb, tgt, mag, row_neg, pair_cnt, pairs, cap);

    pair_kernel<<<256, 256, 0, stream>>>(pairs, pair_cnt, row_neg, cap, loss);

    fin_kernel<<<1, 1, 0, stream>>>(loss, pair_cnt, out);
}